// Round 7
// baseline (834.436 us; speedup 1.0000x reference)
//
#include <hip/hip_runtime.h>
#include <hip/hip_fp16.h>
#include <cmath>

// Problem constants
constexpr int B_ = 64, N_ = 50000, L_ = 8, E_ = 100000, U_ = 20000, G_ = 20000, R_ = 64, D_ = 16, C_ = 2;
constexpr int EPL_ = E_ + 3 * U_ + 8;  // padded edge slots per layer (+8 sentinel tail)
constexpr int NP1 = N_ + 1;            // nodes + zero sentinel row

// Double-buffered h, fp16: buffer q row s lives at flat row (q*NP1 + s).
// Row layout: h[row][b][d], d-contiguous; F = BC*2 float4 chunks per row.
// Parity P[li][s] (batch-independent) is precomputed and baked into ssrc / wdst.

__device__ __forceinline__ float tanh_fast(float x) {
  float e = __expf(2.0f * x);
  return 1.0f - 2.0f * __builtin_amdgcn_rcpf(e + 1.0f);
}

// ---------------- CSR build (batch-independent) ----------------

__global__ __launch_bounds__(256) void hist_kernel(
    const int* __restrict__ dst_pos, int* __restrict__ cnt) {
  int e = blockIdx.x * 256 + threadIdx.x;
  int li = blockIdx.y;
  if (e >= E_) return;
  atomicAdd(&cnt[li * U_ + dst_pos[li * E_ + e]], 1);
}

// Each thread owns 20 contiguous counts; one LDS scan of 1024 partials.
__global__ __launch_bounds__(1024) void scan_kernel(
    const int* __restrict__ cnt, int* __restrict__ offs, int* __restrict__ cursor) {
  __shared__ int sums[1024];
  int li = blockIdx.x, t = threadIdx.x;
  int base = t * 20;
  int v[20];
  int s = 0;
#pragma unroll
  for (int i = 0; i < 20; ++i) {
    int idx = base + i;
    int c = (idx < U_) ? cnt[li * U_ + idx] : 0;
    v[i] = s;
    s += (c + 3) & ~3;
  }
  sums[t] = s;
  __syncthreads();
  for (int off = 1; off < 1024; off <<= 1) {
    int o = (t >= off) ? sums[t - off] : 0;
    __syncthreads();
    sums[t] += o;
    __syncthreads();
  }
  int excl = sums[t] - s;
#pragma unroll
  for (int i = 0; i < 20; ++i) {
    int idx = base + i;
    if (idx < U_) {
      offs[li * (U_ + 1) + idx] = excl + v[i];
      cursor[li * U_ + idx] = excl + v[i];
    }
  }
  if (t == 1023) offs[li * (U_ + 1) + U_] = sums[1023];
}

__global__ __launch_bounds__(256) void scatter_kernel(
    const int* __restrict__ dst_pos, const int* __restrict__ src,
    int* __restrict__ cursor, int* __restrict__ ssrc) {
  int e = blockIdx.x * 256 + threadIdx.x;
  int li = blockIdx.y;
  if (e >= E_) return;
  int u = dst_pos[li * E_ + e];
  int p = atomicAdd(&cursor[li * U_ + u], 1);
  ssrc[(size_t)li * EPL_ + p] = src[li * E_ + e];
}

__global__ __launch_bounds__(256) void pad_fill_k(
    const int* __restrict__ cursor, const int* __restrict__ offs,
    int* __restrict__ ssrc) {
  int t = blockIdx.x * 256 + threadIdx.x;
  if (t >= L_ * U_) return;
  int li = t / U_, u = t % U_;
  int end = cursor[li * U_ + u];
  int pend = offs[li * (U_ + 1) + u + 1];
  int* sp = ssrc + (size_t)li * EPL_;
  for (int p = end; p < pend; ++p) sp[p] = N_;
  if (u == U_ - 1) {
    int ptot = offs[li * (U_ + 1) + U_];
    for (int p = ptot; p < ptot + 8; ++p) sp[p] = N_;
  }
}

// Parity precompute: isdst[li][s] -> P[li][s] (running XOR over layers).
__global__ __launch_bounds__(256) void mark_k(
    const int* __restrict__ dst_unique, char* __restrict__ isdst) {
  int t = blockIdx.x * 256 + threadIdx.x;
  if (t >= L_ * U_) return;
  int li = t / U_;
  isdst[(size_t)li * NP1 + dst_unique[t]] = 1;
}

__global__ __launch_bounds__(256) void ptab_k(
    const char* __restrict__ isdst, char* __restrict__ P) {
  int s = blockIdx.x * 256 + threadIdx.x;
  if (s >= NP1) return;
  char p = 0;
#pragma unroll
  for (int li = 0; li < L_; ++li) {
    P[(size_t)li * NP1 + s] = p;
    p ^= isdst[(size_t)li * NP1 + s];
  }
  P[(size_t)L_ * NP1 + s] = p;
}

// Bake read-buffer parity into ssrc; build write-row table for dst.
__global__ __launch_bounds__(256) void xform_k(
    const int* __restrict__ offs, const char* __restrict__ P,
    int* __restrict__ ssrc) {
  int e = blockIdx.x * 256 + threadIdx.x;
  int li = blockIdx.y;
  if (e >= EPL_) return;
  int ptot = offs[li * (U_ + 1) + U_];
  if (e >= ptot + 8) return;
  int* sp = ssrc + (size_t)li * EPL_;
  int s = sp[e];
  sp[e] = s + NP1 * (int)P[(size_t)li * NP1 + s];
}

__global__ __launch_bounds__(256) void wdst_k(
    const int* __restrict__ dst_unique, const char* __restrict__ P,
    int* __restrict__ wdst) {
  int t = blockIdx.x * 256 + threadIdx.x;
  if (t >= L_ * U_) return;
  int li = t / U_;
  int d = dst_unique[t];
  wdst[t] = d + NP1 * (int)(P[(size_t)li * NP1 + d] ^ 1);
}

// ---------------- Compute ----------------

template <int BC>
__global__ __launch_bounds__(256) void gene_init_k(
    const float* __restrict__ X, const float* __restrict__ w_in,
    const float* __restrict__ b_in, const int* __restrict__ gene_map,
    float4* __restrict__ h4, int c) {
  constexpr int F = BC * 2;
  int t = blockIdx.x * 256 + threadIdx.x;
  if (t >= G_ * BC) return;
  int b = t % BC;
  int g = t / BC;
  float x = X[(c * BC + b) * G_ + g];
  int node = gene_map[g];  // buffer 0 (parity 0 at layer 0)
  float4 out[2];
  __half2* oh = reinterpret_cast<__half2*>(out);
#pragma unroll
  for (int k = 0; k < 8; ++k) {
    float r0 = fmaf(x, w_in[2 * k], b_in[2 * k]);
    float r1 = fmaf(x, w_in[2 * k + 1], b_in[2 * k + 1]);
    oh[k] = __float22half2_rn(make_float2(r0, r1));
  }
  h4[(size_t)node * F + b * 2] = out[0];
  h4[(size_t)node * F + b * 2 + 1] = out[1];
}

// Fused gather + epilogue: each wave owns 4 consecutive u's (contiguous padded
// edge range, buffer-resolved row ids). Flush = @W + bias + tanh -> other h buf.
template <int BC>
__global__ __launch_bounds__(256) void gather_fused_k(
    const float4* __restrict__ h4, float4* __restrict__ hw,
    const int* __restrict__ offs, const int* __restrict__ ssrc,
    const float* __restrict__ W, const float* __restrict__ bias,
    const int* __restrict__ dst_unique, const int* __restrict__ wdst, int li) {
  constexpr int F = BC * 2;
  constexpr int RPL = F / 64;
  __shared__ float Wlds[256];
  int tid = threadIdx.x;
  Wlds[tid] = W[li * 256 + tid];
  __syncthreads();
  int wave = tid >> 6, lane = tid & 63;
  int w = blockIdx.x * 4 + wave;
  int u0 = w * 4;
  const int* ob = offs + li * (U_ + 1) + u0;
  int offv[5];
#pragma unroll
  for (int i = 0; i < 5; ++i) offv[i] = ob[i];
  const int* sp = ssrc + (size_t)li * EPL_;

  int dh = lane & 1;
  int baseA = dh * 136;        // (dh*8+k)*16 + dh*8
  int baseB = 128 - 120 * dh;  // ((1-dh)*8+k)*16 + dh*8 (k term excluded)

  __half2 acc[4][RPL][4];
  const __half2 z = __half2half2(__float2half(0.f));
#pragma unroll
  for (int j = 0; j < 4; ++j)
#pragma unroll
    for (int r = 0; r < RPL; ++r)
#pragma unroll
      for (int k = 0; k < 4; ++k) acc[j][r][k] = z;

  auto flushu = [&](int u) {
    int node = dst_unique[li * U_ + u];
    int wrow = wdst[li * U_ + u];
    const float* bp = bias + (size_t)node * 16 + dh * 8;
    float4 bv0 = *(const float4*)bp;
    float4 bv1 = *(const float4*)(bp + 4);
#pragma unroll
    for (int r = 0; r < RPL; ++r) {
      int f = lane + r * 64;
      float own[8];
#pragma unroll
      for (int k = 0; k < 4; ++k) {
        float2 f0 = __half22float2(acc[0][r][k]);
        float2 f1 = __half22float2(acc[1][r][k]);
        float2 f2 = __half22float2(acc[2][r][k]);
        float2 f3 = __half22float2(acc[3][r][k]);
        own[2 * k] = (f0.x + f1.x) + (f2.x + f3.x);
        own[2 * k + 1] = (f0.y + f1.y) + (f2.y + f3.y);
      }
      float oth[8];
#pragma unroll
      for (int k = 0; k < 4; ++k) {
        __half2 ph = __float22half2_rn(make_float2(own[2 * k], own[2 * k + 1]));
        int pi = *reinterpret_cast<int*>(&ph);
        int qi = __shfl_xor(pi, 1, 64);
        __half2 qh = *reinterpret_cast<__half2*>(&qi);
        float2 ff = __half22float2(qh);
        oth[2 * k] = ff.x;
        oth[2 * k + 1] = ff.y;
      }
      float m[8];
#pragma unroll
      for (int j = 0; j < 8; ++j) m[j] = 0.f;
#pragma unroll
      for (int k = 0; k < 8; ++k) {
        float sA = own[k], sB = oth[k];
        const float4* wa = (const float4*)&Wlds[baseA + k * 16];
        const float4* wb = (const float4*)&Wlds[baseB + k * 16];
        float4 a0 = wa[0], a1 = wa[1], b0 = wb[0], b1 = wb[1];
        m[0] = fmaf(sA, a0.x, fmaf(sB, b0.x, m[0]));
        m[1] = fmaf(sA, a0.y, fmaf(sB, b0.y, m[1]));
        m[2] = fmaf(sA, a0.z, fmaf(sB, b0.z, m[2]));
        m[3] = fmaf(sA, a0.w, fmaf(sB, b0.w, m[3]));
        m[4] = fmaf(sA, a1.x, fmaf(sB, b1.x, m[4]));
        m[5] = fmaf(sA, a1.y, fmaf(sB, b1.y, m[5]));
        m[6] = fmaf(sA, a1.z, fmaf(sB, b1.z, m[6]));
        m[7] = fmaf(sA, a1.w, fmaf(sB, b1.w, m[7]));
      }
      float bb[8] = {bv0.x, bv0.y, bv0.z, bv0.w, bv1.x, bv1.y, bv1.z, bv1.w};
      float4 o;
      __half2* ov = reinterpret_cast<__half2*>(&o);
#pragma unroll
      for (int k = 0; k < 4; ++k) {
        ov[k] = __float22half2_rn(
            make_float2(tanh_fast(m[2 * k] + bb[2 * k]),
                        tanh_fast(m[2 * k + 1] + bb[2 * k + 1])));
      }
      hw[(size_t)wrow * F + f] = o;
    }
#pragma unroll
    for (int j = 0; j < 4; ++j)
#pragma unroll
      for (int r = 0; r < RPL; ++r)
#pragma unroll
        for (int k = 0; k < 4; ++k) acc[j][r][k] = z;
  };

  auto loadRows = [&](float4 (&v)[4][RPL], int4 id) {
    const int* ip = &id.x;
#pragma unroll
    for (int j = 0; j < 4; ++j)
#pragma unroll
      for (int r = 0; r < RPL; ++r)
        v[j][r] = h4[(size_t)ip[j] * F + lane + r * 64];
  };
  auto accum = [&](const float4 (&v)[4][RPL]) {
#pragma unroll
    for (int j = 0; j < 4; ++j)
#pragma unroll
      for (int r = 0; r < RPL; ++r) {
        const __half2* p = reinterpret_cast<const __half2*>(&v[j][r]);
#pragma unroll
        for (int k = 0; k < 4; ++k) acc[j][r][k] = __hadd2(acc[j][r][k], p[k]);
      }
  };

  int e = offv[0];
  int eend = offv[4];
  int uj = 0;
  while (uj < 4 && offv[uj + 1] == e) { flushu(u0 + uj); ++uj; }
  if (e >= eend) return;

  float4 va[4][RPL], vb[4][RPL];
  int4 idC = *(const int4*)(sp + e);
  int4 idN = *(const int4*)(sp + e + 4);  // sentinel tail keeps this in-bounds
  loadRows(va, idC);

  for (;;) {
    loadRows(vb, idN);
    idN = *(const int4*)(sp + e + 8);
    accum(va);
    e += 4;
    if (e == offv[uj + 1]) {
      flushu(u0 + uj); ++uj;
      while (uj < 4 && offv[uj + 1] == e) { flushu(u0 + uj); ++uj; }
    }
    if (e >= eend) break;
    loadRows(va, idN);
    idN = *(const int4*)(sp + e + 8);
    accum(vb);
    e += 4;
    if (e == offv[uj + 1]) {
      flushu(u0 + uj); ++uj;
      while (uj < 4 && offv[uj + 1] == e) { flushu(u0 + uj); ++uj; }
    }
    if (e >= eend) break;
  }
}

template <int BC>
__global__ __launch_bounds__(64) void head_k(
    const float4* __restrict__ h4, const float* __restrict__ W_head,
    const float* __restrict__ b_head, const int* __restrict__ root_ids,
    const char* __restrict__ Pfin, float* __restrict__ out, int c) {
  constexpr int F = BC * 2;
  int bl = blockIdx.x;
  int r = threadIdx.x;
  int node = root_ids[r];
  size_t row = (size_t)node + (size_t)NP1 * Pfin[node];
  float4 p0 = h4[row * F + bl * 2];
  float4 p1 = h4[row * F + bl * 2 + 1];
  float v[16];
  const __half2* ph0 = reinterpret_cast<const __half2*>(&p0);
  const __half2* ph1 = reinterpret_cast<const __half2*>(&p1);
#pragma unroll
  for (int k = 0; k < 4; ++k) {
    float2 f0 = __half22float2(ph0[k]);
    float2 f1 = __half22float2(ph1[k]);
    v[2 * k] = f0.x; v[2 * k + 1] = f0.y;
    v[8 + 2 * k] = f1.x; v[8 + 2 * k + 1] = f1.y;
  }
  float acc0 = 0.f, acc1 = 0.f;
#pragma unroll
  for (int d = 0; d < 16; ++d) {
    acc0 = fmaf(v[d], W_head[r * 16 + d], acc0);
    acc1 = fmaf(v[d], W_head[1024 + r * 16 + d], acc1);
  }
  for (int off = 32; off; off >>= 1) {
    acc0 += __shfl_down(acc0, off, 64);
    acc1 += __shfl_down(acc1, off, 64);
  }
  if (r == 0) {
    out[(c * BC + bl) * 2 + 0] = acc0 + b_head[0];
    out[(c * BC + bl) * 2 + 1] = acc1 + b_head[1];
  }
}

__global__ void zero_out_k(float* out, int n) {
  int t = blockIdx.x * 256 + threadIdx.x;
  if (t < n) out[t] = 0.f;
}

// ---------------- Host side ----------------

static size_t need_bytes(int BC) {
  size_t h = (size_t)2 * NP1 * (BC * 2) * 16;           // two h buffers
  size_t csr = (size_t)L_ * U_ * 4 * 3 +                // cnt, cursor, wdst
               (size_t)L_ * (U_ + 1) * 4 +              // offs
               (size_t)L_ * EPL_ * 4 +                  // ssrc
               (size_t)L_ * NP1 +                       // isdst
               (size_t)(L_ + 1) * NP1 + 256;            // P + slack
  return h + csr;
}

template <int BC>
static void run_all(void* const* d_in, void* d_out, void* d_ws, hipStream_t stream) {
  const float* X = (const float*)d_in[0];
  const float* w_in = (const float*)d_in[1];
  const float* b_in = (const float*)d_in[2];
  const float* W = (const float*)d_in[3];
  const float* bias = (const float*)d_in[4];
  const float* W_head = (const float*)d_in[5];
  const float* b_head = (const float*)d_in[6];
  const int* gene_map = (const int*)d_in[7];
  const int* src = (const int*)d_in[8];
  const int* dst_pos = (const int*)d_in[9];
  const int* dst_unique = (const int*)d_in[10];
  const int* root_ids = (const int*)d_in[11];
  float* out = (float*)d_out;

  constexpr int F = BC * 2;
  const size_t hbuf_bytes = (size_t)NP1 * F * 16;  // one buffer
  char* ws = (char*)d_ws;
  float4* h4 = (float4*)ws;                        // [2][NP1][F]
  char* p = ws + 2 * hbuf_bytes;
  int* cnt = (int*)p;      p += (size_t)L_ * U_ * 4;
  int* cursor = (int*)p;   p += (size_t)L_ * U_ * 4;
  int* wdst = (int*)p;     p += (size_t)L_ * U_ * 4;
  int* offs = (int*)p;     p += (size_t)L_ * (U_ + 1) * 4;
  int* ssrc = (int*)p;     p += (size_t)L_ * EPL_ * 4;
  char* isdst = (char*)p;  p += (size_t)L_ * NP1;
  char* P = (char*)p;

  // CSR + parity build (once, batch-independent)
  hipMemsetAsync(cnt, 0, (size_t)L_ * U_ * 4, stream);
  hipMemsetAsync(isdst, 0, (size_t)L_ * NP1, stream);
  dim3 egrid((E_ + 255) / 256, L_);
  hist_kernel<<<egrid, 256, 0, stream>>>(dst_pos, cnt);
  scan_kernel<<<L_, 1024, 0, stream>>>(cnt, offs, cursor);
  scatter_kernel<<<egrid, 256, 0, stream>>>(dst_pos, src, cursor, ssrc);
  pad_fill_k<<<(L_ * U_ + 255) / 256, 256, 0, stream>>>(cursor, offs, ssrc);
  mark_k<<<(L_ * U_ + 255) / 256, 256, 0, stream>>>(dst_unique, isdst);
  ptab_k<<<(NP1 + 255) / 256, 256, 0, stream>>>(isdst, P);
  dim3 xgrid((EPL_ + 255) / 256, L_);
  xform_k<<<xgrid, 256, 0, stream>>>(offs, P, ssrc);
  wdst_k<<<(L_ * U_ + 255) / 256, 256, 0, stream>>>(dst_unique, P, wdst);

  constexpr int nchunks = B_ / BC;
  const int gather_grid = U_ / 16;  // 4 waves/block, 4 u per wave
  for (int c = 0; c < nchunks; ++c) {
    hipMemsetAsync(h4, 0, hbuf_bytes, stream);  // buffer 0 only
    gene_init_k<BC><<<(G_ * BC + 255) / 256, 256, 0, stream>>>(
        X, w_in, b_in, gene_map, h4, c);
    for (int li = 0; li < L_; ++li) {
      gather_fused_k<BC><<<gather_grid, 256, 0, stream>>>(
          h4, h4, offs, ssrc, W, bias, dst_unique, wdst, li);
    }
    head_k<BC><<<BC, 64, 0, stream>>>(h4, W_head, b_head, root_ids,
                                      P + (size_t)L_ * NP1, out, c);
  }
}

extern "C" void kernel_launch(void* const* d_in, const int* in_sizes, int n_in,
                              void* d_out, int out_size, void* d_ws, size_t ws_size,
                              hipStream_t stream) {
  if (ws_size >= need_bytes(64)) {
    run_all<64>(d_in, d_out, d_ws, stream);
  } else if (ws_size >= need_bytes(32)) {
    run_all<32>(d_in, d_out, d_ws, stream);
  } else if (ws_size >= need_bytes(16)) {
    run_all<16>(d_in, d_out, d_ws, stream);
  } else {
    zero_out_k<<<(out_size + 255) / 256, 256, 0, stream>>>((float*)d_out, out_size);
  }
}